// Round 14
// baseline (101.998 us; speedup 1.0000x reference)
//
#include <hip/hip_runtime.h>
#include <hip/hip_bf16.h>
#include <stdint.h>

typedef float  f32x4 __attribute__((ext_vector_type(4)));
typedef short  s16x8 __attribute__((ext_vector_type(8)));

#define NB    8
#define CIN   64
#define COUT  64
#define HH    128
#define WW    512
#define NTAP  17
#define PADW  152
#define XROW  816            // PADW + WW + PADW
#define BUFB  (XROW * 64)    // 52,224 B per buffer
#define HW    (HH * WW)

// ---------------------------------------------------------------------------
// weights in A-fragment order: byte off = (2t+p)*4096 + m*1024 + lane*16
__global__ __launch_bounds__(256) void prep_wfrag(
        const float* __restrict__ W, const float* __restrict__ Bv,
        __hip_bfloat16* __restrict__ wf, float* __restrict__ bsum) {
    int idx = blockIdx.x * 256 + threadIdx.x;      // 69,632 total
    if (idx < NTAP * 2 * 4 * 64 * 8) {
        int j  = idx & 7;
        int l  = (idx >> 3) & 63;
        int m  = (idx >> 9) & 3;
        int pp = (idx >> 11) & 1;
        int t  = idx >> 12;
        int ci = pp * 32 + 8 * (l >> 4) + j;
        int co = 16 * m + (l & 15);
        float v;
        if (t == 0) {
            v = 0.f;
            #pragma unroll
            for (int i = 0; i < NB; ++i) v += W[((i * COUT + co) * CIN + ci) * 3 + 1];
        } else if (t <= 8) {
            v = W[(((t - 1) * COUT + co) * CIN + ci) * 3 + 0];
        } else {
            v = W[(((t - 9) * COUT + co) * CIN + ci) * 3 + 2];
        }
        wf[idx] = __float2bfloat16(v);
    }
    if (idx < COUT) {
        float s = 0.f;
        #pragma unroll
        for (int i = 0; i < NB; ++i) s += Bv[i * COUT + idx];
        bsum[idx] = s;
    }
}

static constexpr int OFFS[NTAP] = {0, -48, -76, -96, -111, -124, -135, -144, -152,
                                      48,  76,  96,  111,  124,  135,  144,  152};

#define SB __builtin_amdgcn_sched_barrier(0)

#define LOADAF(AF, T0, CNT)                                                    \
    _Pragma("unroll")                                                          \
    for (int i = 0; i < (CNT); ++i)                                            \
        _Pragma("unroll")                                                      \
        for (int m = 0; m < 4; ++m)                                            \
            AF[i][m] = *reinterpret_cast<const s16x8*>(                        \
                wbase + ((T0) + i) * 8192 + m * 1024);

#define COMPTAPS(AF, T0, CNT)                                                  \
    _Pragma("unroll")                                                          \
    for (int i = 0; i < (CNT); ++i) {                                          \
        const int t      = (T0) + i;                                           \
        const int ldsrow = rowb + OFFS[t];                                     \
        const int slot   = lhi ^ ((ldsrow >> 1) & 3);                          \
        const char* bbase = rb + ldsrow * 64 + slot * 16;                      \
        s16x8 bfr[4];                                                          \
        _Pragma("unroll")                                                      \
        for (int n = 0; n < 4; ++n)                                            \
            bfr[n] = *reinterpret_cast<const s16x8*>(bbase + n * 1024);        \
        _Pragma("unroll")                                                      \
        for (int m = 0; m < 4; ++m)                                            \
            _Pragma("unroll")                                                  \
            for (int n = 0; n < 4; ++n)                                        \
                acc[m][n] = __builtin_amdgcn_mfma_f32_16x16x32_bf16(           \
                    AF[i][m], bfr[n], acc[m][n], 0, 0, 0);                     \
    }

// Fused persistent main: 256 blocks x 512 thr (8 waves @ 2/SIMD), m=4 n=4
// (LDS pipe 22us vs m2n8's 43.5us). R12 lesson (in-order vmcnt, m135): ALL
// af batches issued BEFORE SLOAD -> af waits never drain the x-prefetch;
// only the last 2 compute batches follow SLOAD. R13 lesson: SLOAD must stay
// float4 (8 x dwordx4, 1024B/wave-instr) — 32 scalar loads cost ~15us in
// issue/drain pressure. SWRITE keeps R12's wl*4+k rows (known ~2.6us write
// bank conflicts, accepted). x read once fp32, out written once.
__global__ __launch_bounds__(512, 2) void hdc_mfma(
        const float* __restrict__ x, const __hip_bfloat16* __restrict__ wf,
        const float* __restrict__ bsum, float* __restrict__ out) {
    extern __shared__ __align__(16) char smem[];   // 2 * BUFB = 104,448 B

    const int tid  = threadIdx.x;
    const int wv   = tid >> 6;                     // wave 0..7
    const int lane = tid & 63;
    const int l15  = lane & 15;
    const int lhi  = lane >> 4;
    const int c    = tid >> 7;                     // staging chunk 0..3
    const int wl   = tid & 127;                    // staging w/4 index
    const int bh0  = blockIdx.x * 4;               // 4 rows per block
    const int wlo  = wv * 64;                      // wave's 64-w slice (n=4)
    const int rowb = PADW + wlo + l15;

    f32x4 acc[4][4];
    #pragma unroll
    for (int m = 0; m < 4; ++m) {
        f32x4 bi = *reinterpret_cast<const f32x4*>(bsum + 16 * m + 4 * lhi);
        #pragma unroll
        for (int n = 0; n < 4; ++n) acc[m][n] = bi;
    }

    // zero halos once in BOTH buffers (staging writes body rows only)
    {
        const int4 z{0, 0, 0, 0};
        #pragma unroll
        for (int bb = 0; bb < 2; ++bb) {
            int4* base = reinterpret_cast<int4*>(smem + bb * BUFB);
            for (int f = tid; f < 608; f += 512) {
                base[f] = z;                       // left halo  rows [0,152)
                base[2656 + f] = z;                // right halo rows [664,816)
            }
        }
    }

    float4 xv[8];                                  // staged fp32: 8 ci x 4 w

    auto SLOAD = [&](int u) {
        const int r = bh0 + (u >> 1);
        const int b = r >> 7, h = r & 127;
        const float* src = x +
            (((size_t)(b * CIN + (u & 1) * 32 + c * 8) * HH + h) * WW) + wl * 4;
        #pragma unroll
        for (int j = 0; j < 8; ++j)
            xv[j] = *reinterpret_cast<const float4*>(src + j * HW);
    };
    auto SWRITE = [&](int u) {
        char* dst = smem + (u & 1) * BUFB;
        #pragma unroll
        for (int k = 0; k < 4; ++k) {
            const int row  = PADW + wl * 4 + k;
            const int slot = c ^ ((row >> 1) & 3);
            union { __hip_bfloat16 hs[8]; int4 iv; } pk;
            #pragma unroll
            for (int j = 0; j < 8; ++j)
                pk.hs[j] = __float2bfloat16(((const float*)&xv[j])[k]);
            *reinterpret_cast<int4*>(dst + row * 64 + slot * 16) = pk.iv;
        }
    };

    // prologue: fill buf0
    SLOAD(0);
    asm volatile("s_waitcnt vmcnt(0)" ::: "memory");
    SB;
    SWRITE(0);
    __syncthreads();

    for (int u = 0; u < 8; ++u) {
        const char* wbase = (const char*)wf + (u & 1) * 4096 + lane * 16;
        const char* rb    = smem + (u & 1) * BUFB;

        s16x8 afA[3][4], afB[3][4];                // ping-pong af batches

        LOADAF(afA, 0, 3)   SB;
        LOADAF(afB, 3, 3)   SB;
        COMPTAPS(afA, 0, 3) SB;
        LOADAF(afA, 6, 3)   SB;
        COMPTAPS(afB, 3, 3) SB;
        LOADAF(afB, 9, 3)   SB;
        COMPTAPS(afA, 6, 3) SB;
        LOADAF(afA, 12, 3)  SB;
        COMPTAPS(afB, 9, 3) SB;
        LOADAF(afB, 15, 2)  SB;                    // last af load...
        if (u < 7) SLOAD(u + 1);                   // ...then SLOAD = newest vmem
        SB;
        COMPTAPS(afA, 12, 3) SB;                   // waits only afA (older)
        COMPTAPS(afB, 15, 2) SB;                   // waits only afB (older)

        if (u & 1) {
            // row finished: ReLU + store, reinit acc with bias
            const int r = bh0 + (u >> 1);
            const int b = r >> 7, h = r & 127;
            float* obase = out +
                (((size_t)b * COUT + 4 * lhi) * HH + h) * WW + wlo + l15;
            #pragma unroll
            for (int m = 0; m < 4; ++m)
                #pragma unroll
                for (int n = 0; n < 4; ++n)
                    #pragma unroll
                    for (int rr = 0; rr < 4; ++rr) {
                        float v = acc[m][n][rr];
                        obase[(size_t)(16 * m + rr) * HW + 16 * n] =
                            v > 0.f ? v : 0.f;
                    }
            #pragma unroll
            for (int m = 0; m < 4; ++m) {
                f32x4 bi = *reinterpret_cast<const f32x4*>(bsum + 16 * m + 4 * lhi);
                #pragma unroll
                for (int n = 0; n < 4; ++n) acc[m][n] = bi;
            }
        }

        if (u < 7) {
            asm volatile("s_waitcnt vmcnt(0)" ::: "memory");   // xv landed
            SB;
            SWRITE(u + 1);                         // into buf[(u+1)&1]
        }

        asm volatile("s_waitcnt lgkmcnt(0)" ::: "memory");     // ds_writes done
        SB;
        __builtin_amdgcn_s_barrier();              // buf ready for all waves
    }
}

// ---------------------------------------------------------------------------
// FALLBACK (round-1 fp32 kernel) if ws_size is too small for weight scratch
// ---------------------------------------------------------------------------
#define CI_STAGE 16

__global__ void prep_weff_fb(const float* __restrict__ W, const float* __restrict__ Bv,
                             float* __restrict__ weff, float* __restrict__ bsum) {
    int idx = blockIdx.x * 256 + threadIdx.x;
    if (idx < CIN * NTAP * COUT) {
        int co = idx & 63;
        int t  = (idx >> 6) % NTAP;
        int ci = idx / (NTAP * COUT);
        float v;
        if (t == 0) {
            v = 0.f;
            #pragma unroll
            for (int i = 0; i < NB; ++i) v += W[(((i * COUT + co) * CIN + ci) * 3) + 1];
        } else if (t <= 8) {
            v = W[((((t - 1) * COUT + co) * CIN + ci) * 3) + 0];
        } else {
            v = W[((((t - 9) * COUT + co) * CIN + ci) * 3) + 2];
        }
        weff[(ci * NTAP + t) * COUT + co] = v;
    }
    if (idx < COUT) {
        float s = 0.f;
        #pragma unroll
        for (int i = 0; i < NB; ++i) s += Bv[i * COUT + idx];
        bsum[idx] = s;
    }
}

__global__ __launch_bounds__(256, 2) void hdc_fb(
        const float* __restrict__ x, const float* __restrict__ weff,
        const float* __restrict__ bsum, float* __restrict__ out) {
    __shared__ float xsf[CI_STAGE][XROW];
    const int bh  = blockIdx.x;
    const int b   = bh >> 7;
    const int h   = bh & (HH - 1);
    const int tid = threadIdx.x;
    const int cg  = tid >> 5;
    const int wl  = tid & 31;
    float acc[8][16];
    #pragma unroll
    for (int j = 0; j < 8; ++j) {
        const float bj = bsum[cg * 8 + j];
        #pragma unroll
        for (int i = 0; i < 16; ++i) acc[j][i] = bj;
    }
    const float* xrowbase = x + ((size_t)(b * CIN) * HH + h) * WW;
    for (int s = 0; s < CIN / CI_STAGE; ++s) {
        __syncthreads();
        for (int f = tid; f < CI_STAGE * PADW; f += 256) {
            int r = f / PADW, cc = f - r * PADW;
            xsf[r][cc] = 0.f;
            xsf[r][PADW + WW + cc] = 0.f;
        }
        #pragma unroll
        for (int j = 0; j < 8; ++j) {
            int flat = j * 256 + tid;
            int r = flat >> 7, c4 = flat & 127;
            const float4 v = *reinterpret_cast<const float4*>(
                xrowbase + (size_t)(s * CI_STAGE + r) * HW + c4 * 4);
            *reinterpret_cast<float4*>(&xsf[r][PADW + c4 * 4]) = v;
        }
        __syncthreads();
        for (int r = 0; r < CI_STAGE; ++r) {
            const int ci = s * CI_STAGE + r;
            const float* wrow = weff + (size_t)(ci * NTAP) * COUT + cg * 8;
            const float* xr   = &xsf[r][PADW + wl];
            #pragma unroll
            for (int t = 0; t < NTAP; ++t) {
                const float4 w0 = *reinterpret_cast<const float4*>(wrow + t * COUT);
                const float4 w1 = *reinterpret_cast<const float4*>(wrow + t * COUT + 4);
                float xvv[16];
                #pragma unroll
                for (int i = 0; i < 16; ++i) xvv[i] = xr[OFFS[t] + 32 * i];
                const float wv2[8] = {w0.x, w0.y, w0.z, w0.w, w1.x, w1.y, w1.z, w1.w};
                #pragma unroll
                for (int j = 0; j < 8; ++j)
                    #pragma unroll
                    for (int i = 0; i < 16; ++i)
                        acc[j][i] = fmaf(wv2[j], xvv[i], acc[j][i]);
            }
        }
    }
    float* outbase = out + (((size_t)b * COUT + cg * 8) * HH + h) * WW + wl;
    #pragma unroll
    for (int j = 0; j < 8; ++j)
        #pragma unroll
        for (int i = 0; i < 16; ++i) {
            float v = acc[j][i];
            outbase[(size_t)j * HW + 32 * i] = v > 0.f ? v : 0.f;
        }
}

// ---------------------------------------------------------------------------

extern "C" void kernel_launch(void* const* d_in, const int* in_sizes, int n_in,
                              void* d_out, int out_size, void* d_ws, size_t ws_size,
                              hipStream_t stream) {
    const float* x  = (const float*)d_in[0];
    const float* W  = (const float*)d_in[1];
    const float* Bv = (const float*)d_in[2];
    float* out = (float*)d_out;

    const size_t need = 139264 + 256;              // wf + bsum

    if (ws_size >= need) {
        __hip_bfloat16* wf = (__hip_bfloat16*)d_ws;               // 139,264 B
        float* bsum = (float*)((char*)d_ws + 139264);             // 256 B
        prep_wfrag<<<272, 256, 0, stream>>>(W, Bv, wf, bsum);
        (void)hipFuncSetAttribute((const void*)hdc_mfma,
            hipFuncAttributeMaxDynamicSharedMemorySize, 2 * BUFB);
        hdc_mfma<<<256, 512, 2 * BUFB, stream>>>(x, wf, bsum, out);
    } else {
        float* weff = (float*)d_ws;
        float* bsum = weff + (size_t)CIN * NTAP * COUT;
        prep_weff_fb<<<(CIN * NTAP * COUT + 255) / 256, 256, 0, stream>>>(W, Bv, weff, bsum);
        hdc_fb<<<NB * HH, 256, 0, stream>>>(x, weff, bsum, out);
    }
}

// Round 15
// 77.762 us; speedup vs baseline: 1.3117x; 1.3117x over previous
//
#include <hip/hip_runtime.h>
#include <hip/hip_bf16.h>
#include <stdint.h>

typedef float  f32x4 __attribute__((ext_vector_type(4)));
typedef short  s16x8 __attribute__((ext_vector_type(8)));

#define NB    8
#define CIN   64
#define COUT  64
#define HH    128
#define WW    512
#define NTAP  17
#define PADW  152
#define XROW  816            // PADW + WW + PADW
#define BUFB  (XROW * 64)    // 52,224 B per buffer
#define HW    (HH * WW)

// ---------------------------------------------------------------------------
// weights in A-fragment order: byte off = (2t+p)*4096 + m*1024 + lane*16
__global__ __launch_bounds__(256) void prep_wfrag(
        const float* __restrict__ W, const float* __restrict__ Bv,
        __hip_bfloat16* __restrict__ wf, float* __restrict__ bsum) {
    int idx = blockIdx.x * 256 + threadIdx.x;      // 69,632 total
    if (idx < NTAP * 2 * 4 * 64 * 8) {
        int j  = idx & 7;
        int l  = (idx >> 3) & 63;
        int m  = (idx >> 9) & 3;
        int pp = (idx >> 11) & 1;
        int t  = idx >> 12;
        int ci = pp * 32 + 8 * (l >> 4) + j;
        int co = 16 * m + (l & 15);
        float v;
        if (t == 0) {
            v = 0.f;
            #pragma unroll
            for (int i = 0; i < NB; ++i) v += W[((i * COUT + co) * CIN + ci) * 3 + 1];
        } else if (t <= 8) {
            v = W[(((t - 1) * COUT + co) * CIN + ci) * 3 + 0];
        } else {
            v = W[(((t - 9) * COUT + co) * CIN + ci) * 3 + 2];
        }
        wf[idx] = __float2bfloat16(v);
    }
    if (idx < COUT) {
        float s = 0.f;
        #pragma unroll
        for (int i = 0; i < NB; ++i) s += Bv[i * COUT + idx];
        bsum[idx] = s;
    }
}

static constexpr int OFFS[NTAP] = {0, -48, -76, -96, -111, -124, -135, -144, -152,
                                      48,  76,  96,  111,  124,  135,  144,  152};

#define SB __builtin_amdgcn_sched_barrier(0)

#define LOADAF(AF, T0, CNT)                                                    \
    _Pragma("unroll")                                                          \
    for (int i = 0; i < (CNT); ++i)                                            \
        _Pragma("unroll")                                                      \
        for (int mm = 0; mm < 2; ++mm)                                         \
            AF[i][mm] = *reinterpret_cast<const s16x8*>(                       \
                wbase + ((T0) + i) * 8192 + (2 * mg + mm) * 1024);

#define COMPTAPS(AF, T0, CNT)                                                  \
    _Pragma("unroll")                                                          \
    for (int i = 0; i < (CNT); ++i) {                                          \
        const int t      = (T0) + i;                                           \
        const int ldsrow = rowb + OFFS[t];                                     \
        const int slot   = lhi ^ ((ldsrow >> 1) & 3);                          \
        const char* bbase = rb + ldsrow * 64 + slot * 16;                      \
        s16x8 bfr[8];                                                          \
        _Pragma("unroll")                                                      \
        for (int n = 0; n < 8; ++n)                                            \
            bfr[n] = *reinterpret_cast<const s16x8*>(bbase + n * 1024);        \
        _Pragma("unroll")                                                      \
        for (int mm = 0; mm < 2; ++mm)                                         \
            _Pragma("unroll")                                                  \
            for (int n = 0; n < 8; ++n)                                        \
                acc[mm][n] = __builtin_amdgcn_mfma_f32_16x16x32_bf16(          \
                    AF[i][mm], bfr[n], acc[mm][n], 0, 0, 0);                   \
    }

// One unit's pipelined schedule: 6 tap-batches, af ping-pong, SLOAD early.
// (B_i, C_i) = (tap base, count) — different per mg group (wave desync).
#define UNIT_SCHED(U, B1,C1, B2,C2, B3,C3, B4,C4, B5,C5, B6,C6)                \
    {                                                                          \
        s16x8 afA[3][2], afB[3][2];                                            \
        LOADAF(afA, B1, C1)   SB;                                              \
        LOADAF(afB, B2, C2)   SB;                                              \
        if ((U) < 7) SLOAD((U) + 1);                                           \
        SB;                                                                    \
        COMPTAPS(afA, B1, C1) SB;                                              \
        LOADAF(afA, B3, C3)   SB;                                              \
        COMPTAPS(afB, B2, C2) SB;                                              \
        LOADAF(afB, B4, C4)   SB;                                              \
        COMPTAPS(afA, B3, C3) SB;                                              \
        LOADAF(afA, B5, C5)   SB;                                              \
        COMPTAPS(afB, B4, C4) SB;                                              \
        LOADAF(afB, B6, C6)   SB;                                              \
        COMPTAPS(afA, B5, C5) SB;                                              \
        COMPTAPS(afB, B6, C6) SB;                                              \
    }

// Fused persistent main (R11 base = best measured, m=2 n=8, 8 waves @ 2/SIMD)
// + ONE change: mg-group tap rotation. SIMD i hosts waves i (mg=0) and i+4
// (mg=1); giving them rotated tap orders (0..16 vs 9..16,0..8) makes the two
// co-resident waves permanently out of phase so one wave's MFMA burst covers
// the other's ds_read burst (the lockstep-symmetric schedule left both pipes
// at ~55% duty — R11-R14 analysis). Tap sum order only affects bf16 rounding.
__global__ __launch_bounds__(512, 2) void hdc_mfma(
        const float* __restrict__ x, const __hip_bfloat16* __restrict__ wf,
        const float* __restrict__ bsum, float* __restrict__ out) {
    extern __shared__ __align__(16) char smem[];   // 2 * BUFB = 104,448 B

    const int tid  = threadIdx.x;
    const int wv   = tid >> 6;                     // wave 0..7
    const int lane = tid & 63;
    const int l15  = lane & 15;
    const int lhi  = lane >> 4;
    const int mg   = wv >> 2;                      // m-pair 0/1 (co 32-half)
    const int ws   = wv & 3;                       // w-slice 0..3
    const int c    = tid >> 7;                     // staging chunk 0..3
    const int wl   = tid & 127;                    // staging w/4 index
    const int bh0  = blockIdx.x * 4;               // 4 rows per block
    const int wlo  = ws * 128;
    const int rowb = PADW + wlo + l15;

    f32x4 acc[2][8];
    #pragma unroll
    for (int mm = 0; mm < 2; ++mm) {
        f32x4 bi = *reinterpret_cast<const f32x4*>(
            bsum + mg * 32 + 16 * mm + 4 * lhi);
        #pragma unroll
        for (int n = 0; n < 8; ++n) acc[mm][n] = bi;
    }

    // zero halos once in BOTH buffers (staging writes body rows only)
    {
        const int4 z{0, 0, 0, 0};
        #pragma unroll
        for (int bb = 0; bb < 2; ++bb) {
            int4* base = reinterpret_cast<int4*>(smem + bb * BUFB);
            for (int f = tid; f < 608; f += 512) {
                base[f] = z;                       // left halo  rows [0,152)
                base[2656 + f] = z;                // right halo rows [664,816)
            }
        }
    }

    float4 xv[8];                                  // staged fp32: 8 ci x 4 w

    auto SLOAD = [&](int u) {
        const int r = bh0 + (u >> 1);
        const int b = r >> 7, h = r & 127;
        const float* src = x +
            (((size_t)(b * CIN + (u & 1) * 32 + c * 8) * HH + h) * WW) + wl * 4;
        #pragma unroll
        for (int j = 0; j < 8; ++j)
            xv[j] = *reinterpret_cast<const float4*>(src + j * HW);
    };
    auto SWRITE = [&](int u) {
        char* dst = smem + (u & 1) * BUFB;
        #pragma unroll
        for (int k = 0; k < 4; ++k) {
            const int row  = PADW + wl * 4 + k;
            const int slot = c ^ ((row >> 1) & 3);
            union { __hip_bfloat16 hs[8]; int4 iv; } pk;
            #pragma unroll
            for (int j = 0; j < 8; ++j)
                pk.hs[j] = __float2bfloat16(((const float*)&xv[j])[k]);
            *reinterpret_cast<int4*>(dst + row * 64 + slot * 16) = pk.iv;
        }
    };

    // prologue: fill buf0
    SLOAD(0);
    asm volatile("s_waitcnt vmcnt(0)" ::: "memory");
    SB;
    SWRITE(0);
    __syncthreads();

    for (int u = 0; u < 8; ++u) {
        const char* wbase = (const char*)wf + (u & 1) * 4096 + lane * 16;
        const char* rb    = smem + (u & 1) * BUFB;

        if (mg == 0) {
            UNIT_SCHED(u, 0,3, 3,3, 6,3, 9,3, 12,3, 15,2)
        } else {
            UNIT_SCHED(u, 9,3, 12,3, 15,2, 0,3, 3,3, 6,3)
        }

        if (u & 1) {
            // row finished: ReLU + store, reinit acc with bias
            const int r = bh0 + (u >> 1);
            const int b = r >> 7, h = r & 127;
            float* obase = out +
                (((size_t)b * COUT + mg * 32 + 4 * lhi) * HH + h) * WW + wlo + l15;
            #pragma unroll
            for (int mm = 0; mm < 2; ++mm)
                #pragma unroll
                for (int n = 0; n < 8; ++n)
                    #pragma unroll
                    for (int rr = 0; rr < 4; ++rr) {
                        float v = acc[mm][n][rr];
                        obase[(size_t)(16 * mm + rr) * HW + 16 * n] =
                            v > 0.f ? v : 0.f;
                    }
            #pragma unroll
            for (int mm = 0; mm < 2; ++mm) {
                f32x4 bi = *reinterpret_cast<const f32x4*>(
                    bsum + mg * 32 + 16 * mm + 4 * lhi);
                #pragma unroll
                for (int n = 0; n < 8; ++n) acc[mm][n] = bi;
            }
        }

        if (u < 7) {
            asm volatile("s_waitcnt vmcnt(0)" ::: "memory");   // xv landed
            SB;
            SWRITE(u + 1);                         // into buf[(u+1)&1]
        }

        asm volatile("s_waitcnt lgkmcnt(0)" ::: "memory");     // ds_writes done
        SB;
        __builtin_amdgcn_s_barrier();              // buf ready for all waves
    }
}

// ---------------------------------------------------------------------------
// FALLBACK (round-1 fp32 kernel) if ws_size is too small for weight scratch
// ---------------------------------------------------------------------------
#define CI_STAGE 16

__global__ void prep_weff_fb(const float* __restrict__ W, const float* __restrict__ Bv,
                             float* __restrict__ weff, float* __restrict__ bsum) {
    int idx = blockIdx.x * 256 + threadIdx.x;
    if (idx < CIN * NTAP * COUT) {
        int co = idx & 63;
        int t  = (idx >> 6) % NTAP;
        int ci = idx / (NTAP * COUT);
        float v;
        if (t == 0) {
            v = 0.f;
            #pragma unroll
            for (int i = 0; i < NB; ++i) v += W[(((i * COUT + co) * CIN + ci) * 3) + 1];
        } else if (t <= 8) {
            v = W[((((t - 1) * COUT + co) * CIN + ci) * 3) + 0];
        } else {
            v = W[((((t - 9) * COUT + co) * CIN + ci) * 3) + 2];
        }
        weff[(ci * NTAP + t) * COUT + co] = v;
    }
    if (idx < COUT) {
        float s = 0.f;
        #pragma unroll
        for (int i = 0; i < NB; ++i) s += Bv[i * COUT + idx];
        bsum[idx] = s;
    }
}

__global__ __launch_bounds__(256, 2) void hdc_fb(
        const float* __restrict__ x, const float* __restrict__ weff,
        const float* __restrict__ bsum, float* __restrict__ out) {
    __shared__ float xsf[CI_STAGE][XROW];
    const int bh  = blockIdx.x;
    const int b   = bh >> 7;
    const int h   = bh & (HH - 1);
    const int tid = threadIdx.x;
    const int cg  = tid >> 5;
    const int wl  = tid & 31;
    float acc[8][16];
    #pragma unroll
    for (int j = 0; j < 8; ++j) {
        const float bj = bsum[cg * 8 + j];
        #pragma unroll
        for (int i = 0; i < 16; ++i) acc[j][i] = bj;
    }
    const float* xrowbase = x + ((size_t)(b * CIN) * HH + h) * WW;
    for (int s = 0; s < CIN / CI_STAGE; ++s) {
        __syncthreads();
        for (int f = tid; f < CI_STAGE * PADW; f += 256) {
            int r = f / PADW, cc = f - r * PADW;
            xsf[r][cc] = 0.f;
            xsf[r][PADW + WW + cc] = 0.f;
        }
        #pragma unroll
        for (int j = 0; j < 8; ++j) {
            int flat = j * 256 + tid;
            int r = flat >> 7, c4 = flat & 127;
            const float4 v = *reinterpret_cast<const float4*>(
                xrowbase + (size_t)(s * CI_STAGE + r) * HW + c4 * 4);
            *reinterpret_cast<float4*>(&xsf[r][PADW + c4 * 4]) = v;
        }
        __syncthreads();
        for (int r = 0; r < CI_STAGE; ++r) {
            const int ci = s * CI_STAGE + r;
            const float* wrow = weff + (size_t)(ci * NTAP) * COUT + cg * 8;
            const float* xr   = &xsf[r][PADW + wl];
            #pragma unroll
            for (int t = 0; t < NTAP; ++t) {
                const float4 w0 = *reinterpret_cast<const float4*>(wrow + t * COUT);
                const float4 w1 = *reinterpret_cast<const float4*>(wrow + t * COUT + 4);
                float xvv[16];
                #pragma unroll
                for (int i = 0; i < 16; ++i) xvv[i] = xr[OFFS[t] + 32 * i];
                const float wv2[8] = {w0.x, w0.y, w0.z, w0.w, w1.x, w1.y, w1.z, w1.w};
                #pragma unroll
                for (int j = 0; j < 8; ++j)
                    #pragma unroll
                    for (int i = 0; i < 16; ++i)
                        acc[j][i] = fmaf(wv2[j], xvv[i], acc[j][i]);
            }
        }
    }
    float* outbase = out + (((size_t)b * COUT + cg * 8) * HH + h) * WW + wl;
    #pragma unroll
    for (int j = 0; j < 8; ++j)
        #pragma unroll
        for (int i = 0; i < 16; ++i) {
            float v = acc[j][i];
            outbase[(size_t)j * HW + 32 * i] = v > 0.f ? v : 0.f;
        }
}

// ---------------------------------------------------------------------------

extern "C" void kernel_launch(void* const* d_in, const int* in_sizes, int n_in,
                              void* d_out, int out_size, void* d_ws, size_t ws_size,
                              hipStream_t stream) {
    const float* x  = (const float*)d_in[0];
    const float* W  = (const float*)d_in[1];
    const float* Bv = (const float*)d_in[2];
    float* out = (float*)d_out;

    const size_t need = 139264 + 256;              // wf + bsum

    if (ws_size >= need) {
        __hip_bfloat16* wf = (__hip_bfloat16*)d_ws;               // 139,264 B
        float* bsum = (float*)((char*)d_ws + 139264);             // 256 B
        prep_wfrag<<<272, 256, 0, stream>>>(W, Bv, wf, bsum);
        (void)hipFuncSetAttribute((const void*)hdc_mfma,
            hipFuncAttributeMaxDynamicSharedMemorySize, 2 * BUFB);
        hdc_mfma<<<256, 512, 2 * BUFB, stream>>>(x, wf, bsum, out);
    } else {
        float* weff = (float*)d_ws;
        float* bsum = weff + (size_t)CIN * NTAP * COUT;
        prep_weff_fb<<<(CIN * NTAP * COUT + 255) / 256, 256, 0, stream>>>(W, Bv, weff, bsum);
        hdc_fb<<<NB * HH, 256, 0, stream>>>(x, weff, bsum, out);
    }
}

// Round 16
// 77.418 us; speedup vs baseline: 1.3175x; 1.0044x over previous
//
#include <hip/hip_runtime.h>
#include <hip/hip_bf16.h>
#include <stdint.h>

typedef float  f32x4 __attribute__((ext_vector_type(4)));
typedef short  s16x8 __attribute__((ext_vector_type(8)));

#define NB    8
#define CIN   64
#define COUT  64
#define HH    128
#define WW    512
#define NTAP  17
#define PADW  152
#define XROW  816            // PADW + WW + PADW
#define BUFB  (XROW * 64)    // 52,224 B per buffer
#define HW    (HH * WW)

// ---------------------------------------------------------------------------
// weights in A-fragment order: byte off = (2t+p)*4096 + m*1024 + lane*16
__global__ __launch_bounds__(256) void prep_wfrag(
        const float* __restrict__ W, const float* __restrict__ Bv,
        __hip_bfloat16* __restrict__ wf, float* __restrict__ bsum) {
    int idx = blockIdx.x * 256 + threadIdx.x;      // 69,632 total
    if (idx < NTAP * 2 * 4 * 64 * 8) {
        int j  = idx & 7;
        int l  = (idx >> 3) & 63;
        int m  = (idx >> 9) & 3;
        int pp = (idx >> 11) & 1;
        int t  = idx >> 12;
        int ci = pp * 32 + 8 * (l >> 4) + j;
        int co = 16 * m + (l & 15);
        float v;
        if (t == 0) {
            v = 0.f;
            #pragma unroll
            for (int i = 0; i < NB; ++i) v += W[((i * COUT + co) * CIN + ci) * 3 + 1];
        } else if (t <= 8) {
            v = W[(((t - 1) * COUT + co) * CIN + ci) * 3 + 0];
        } else {
            v = W[(((t - 9) * COUT + co) * CIN + ci) * 3 + 2];
        }
        wf[idx] = __float2bfloat16(v);
    }
    if (idx < COUT) {
        float s = 0.f;
        #pragma unroll
        for (int i = 0; i < NB; ++i) s += Bv[i * COUT + idx];
        bsum[idx] = s;
    }
}

static constexpr int OFFS[NTAP] = {0, -48, -76, -96, -111, -124, -135, -144, -152,
                                      48,  76,  96,  111,  124,  135,  144,  152};

#define SB __builtin_amdgcn_sched_barrier(0)

#define LOADAF(AF, T0, CNT)                                                    \
    _Pragma("unroll")                                                          \
    for (int i = 0; i < (CNT); ++i)                                            \
        _Pragma("unroll")                                                      \
        for (int mm = 0; mm < 2; ++mm)                                         \
            AF[i][mm] = *reinterpret_cast<const s16x8*>(                       \
                wbase + ((T0) + i) * 8192 + (2 * mg + mm) * 1024);

#define COMPTAPS(AF, T0, CNT)                                                  \
    __builtin_amdgcn_s_setprio(1);                                             \
    _Pragma("unroll")                                                          \
    for (int i = 0; i < (CNT); ++i) {                                          \
        const int t      = (T0) + i;                                           \
        const int ldsrow = rowb + OFFS[t];                                     \
        const int slot   = lhi ^ ((ldsrow >> 1) & 3);                          \
        const char* bbase = rb + ldsrow * 64 + slot * 16;                      \
        s16x8 bfr[8];                                                          \
        _Pragma("unroll")                                                      \
        for (int n = 0; n < 8; ++n)                                            \
            bfr[n] = *reinterpret_cast<const s16x8*>(bbase + n * 1024);        \
        _Pragma("unroll")                                                      \
        for (int mm = 0; mm < 2; ++mm)                                         \
            _Pragma("unroll")                                                  \
            for (int n = 0; n < 8; ++n)                                        \
                acc[mm][n] = __builtin_amdgcn_mfma_f32_16x16x32_bf16(          \
                    AF[i][mm], bfr[n], acc[mm][n], 0, 0, 0);                   \
    }                                                                          \
    __builtin_amdgcn_s_setprio(0);

// One unit's pipelined schedule: 6 tap-batches, af ping-pong, SLOAD early.
// (B_i, C_i) = (tap base, count) — different per mg group (wave desync).
#define UNIT_SCHED(U, B1,C1, B2,C2, B3,C3, B4,C4, B5,C5, B6,C6)                \
    {                                                                          \
        s16x8 afA[3][2], afB[3][2];                                            \
        LOADAF(afA, B1, C1)   SB;                                              \
        LOADAF(afB, B2, C2)   SB;                                              \
        if ((U) < 7) SLOAD((U) + 1);                                           \
        SB;                                                                    \
        COMPTAPS(afA, B1, C1) SB;                                              \
        LOADAF(afA, B3, C3)   SB;                                              \
        COMPTAPS(afB, B2, C2) SB;                                              \
        LOADAF(afB, B4, C4)   SB;                                              \
        COMPTAPS(afA, B3, C3) SB;                                              \
        LOADAF(afA, B5, C5)   SB;                                              \
        COMPTAPS(afB, B4, C4) SB;                                              \
        LOADAF(afB, B6, C6)   SB;                                              \
        COMPTAPS(afA, B5, C5) SB;                                              \
        COMPTAPS(afB, B6, C6) SB;                                              \
    }

// Fused persistent main (R15 base = best measured: m=2 n=8, 8 waves @ 2/SIMD,
// mg-group tap rotation for wave desync) + ONE change: T5 s_setprio(1/0)
// around each MFMA batch. R15's desync created wave role-diversity (one
// co-resident wave in MFMA burst while the other is in ds_read/af burst) —
// the catalog's precondition for setprio to pay (null on lockstep, m190;
// +21-39% on role-split schedules, m218b/m224). Zero-risk lever.
__global__ __launch_bounds__(512, 2) void hdc_mfma(
        const float* __restrict__ x, const __hip_bfloat16* __restrict__ wf,
        const float* __restrict__ bsum, float* __restrict__ out) {
    extern __shared__ __align__(16) char smem[];   // 2 * BUFB = 104,448 B

    const int tid  = threadIdx.x;
    const int wv   = tid >> 6;                     // wave 0..7
    const int lane = tid & 63;
    const int l15  = lane & 15;
    const int lhi  = lane >> 4;
    const int mg   = wv >> 2;                      // m-pair 0/1 (co 32-half)
    const int ws   = wv & 3;                       // w-slice 0..3
    const int c    = tid >> 7;                     // staging chunk 0..3
    const int wl   = tid & 127;                    // staging w/4 index
    const int bh0  = blockIdx.x * 4;               // 4 rows per block
    const int wlo  = ws * 128;
    const int rowb = PADW + wlo + l15;

    f32x4 acc[2][8];
    #pragma unroll
    for (int mm = 0; mm < 2; ++mm) {
        f32x4 bi = *reinterpret_cast<const f32x4*>(
            bsum + mg * 32 + 16 * mm + 4 * lhi);
        #pragma unroll
        for (int n = 0; n < 8; ++n) acc[mm][n] = bi;
    }

    // zero halos once in BOTH buffers (staging writes body rows only)
    {
        const int4 z{0, 0, 0, 0};
        #pragma unroll
        for (int bb = 0; bb < 2; ++bb) {
            int4* base = reinterpret_cast<int4*>(smem + bb * BUFB);
            for (int f = tid; f < 608; f += 512) {
                base[f] = z;                       // left halo  rows [0,152)
                base[2656 + f] = z;                // right halo rows [664,816)
            }
        }
    }

    float4 xv[8];                                  // staged fp32: 8 ci x 4 w

    auto SLOAD = [&](int u) {
        const int r = bh0 + (u >> 1);
        const int b = r >> 7, h = r & 127;
        const float* src = x +
            (((size_t)(b * CIN + (u & 1) * 32 + c * 8) * HH + h) * WW) + wl * 4;
        #pragma unroll
        for (int j = 0; j < 8; ++j)
            xv[j] = *reinterpret_cast<const float4*>(src + j * HW);
    };
    auto SWRITE = [&](int u) {
        char* dst = smem + (u & 1) * BUFB;
        #pragma unroll
        for (int k = 0; k < 4; ++k) {
            const int row  = PADW + wl * 4 + k;
            const int slot = c ^ ((row >> 1) & 3);
            union { __hip_bfloat16 hs[8]; int4 iv; } pk;
            #pragma unroll
            for (int j = 0; j < 8; ++j)
                pk.hs[j] = __float2bfloat16(((const float*)&xv[j])[k]);
            *reinterpret_cast<int4*>(dst + row * 64 + slot * 16) = pk.iv;
        }
    };

    // prologue: fill buf0
    SLOAD(0);
    asm volatile("s_waitcnt vmcnt(0)" ::: "memory");
    SB;
    SWRITE(0);
    __syncthreads();

    for (int u = 0; u < 8; ++u) {
        const char* wbase = (const char*)wf + (u & 1) * 4096 + lane * 16;
        const char* rb    = smem + (u & 1) * BUFB;

        if (mg == 0) {
            UNIT_SCHED(u, 0,3, 3,3, 6,3, 9,3, 12,3, 15,2)
        } else {
            UNIT_SCHED(u, 9,3, 12,3, 15,2, 0,3, 3,3, 6,3)
        }

        if (u & 1) {
            // row finished: ReLU + store, reinit acc with bias
            const int r = bh0 + (u >> 1);
            const int b = r >> 7, h = r & 127;
            float* obase = out +
                (((size_t)b * COUT + mg * 32 + 4 * lhi) * HH + h) * WW + wlo + l15;
            #pragma unroll
            for (int mm = 0; mm < 2; ++mm)
                #pragma unroll
                for (int n = 0; n < 8; ++n)
                    #pragma unroll
                    for (int rr = 0; rr < 4; ++rr) {
                        float v = acc[mm][n][rr];
                        obase[(size_t)(16 * mm + rr) * HW + 16 * n] =
                            v > 0.f ? v : 0.f;
                    }
            #pragma unroll
            for (int mm = 0; mm < 2; ++mm) {
                f32x4 bi = *reinterpret_cast<const f32x4*>(
                    bsum + mg * 32 + 16 * mm + 4 * lhi);
                #pragma unroll
                for (int n = 0; n < 8; ++n) acc[mm][n] = bi;
            }
        }

        if (u < 7) {
            asm volatile("s_waitcnt vmcnt(0)" ::: "memory");   // xv landed
            SB;
            SWRITE(u + 1);                         // into buf[(u+1)&1]
        }

        asm volatile("s_waitcnt lgkmcnt(0)" ::: "memory");     // ds_writes done
        SB;
        __builtin_amdgcn_s_barrier();              // buf ready for all waves
    }
}

// ---------------------------------------------------------------------------
// FALLBACK (round-1 fp32 kernel) if ws_size is too small for weight scratch
// ---------------------------------------------------------------------------
#define CI_STAGE 16

__global__ void prep_weff_fb(const float* __restrict__ W, const float* __restrict__ Bv,
                             float* __restrict__ weff, float* __restrict__ bsum) {
    int idx = blockIdx.x * 256 + threadIdx.x;
    if (idx < CIN * NTAP * COUT) {
        int co = idx & 63;
        int t  = (idx >> 6) % NTAP;
        int ci = idx / (NTAP * COUT);
        float v;
        if (t == 0) {
            v = 0.f;
            #pragma unroll
            for (int i = 0; i < NB; ++i) v += W[(((i * COUT + co) * CIN + ci) * 3) + 1];
        } else if (t <= 8) {
            v = W[((((t - 1) * COUT + co) * CIN + ci) * 3) + 0];
        } else {
            v = W[((((t - 9) * COUT + co) * CIN + ci) * 3) + 2];
        }
        weff[(ci * NTAP + t) * COUT + co] = v;
    }
    if (idx < COUT) {
        float s = 0.f;
        #pragma unroll
        for (int i = 0; i < NB; ++i) s += Bv[i * COUT + idx];
        bsum[idx] = s;
    }
}

__global__ __launch_bounds__(256, 2) void hdc_fb(
        const float* __restrict__ x, const float* __restrict__ weff,
        const float* __restrict__ bsum, float* __restrict__ out) {
    __shared__ float xsf[CI_STAGE][XROW];
    const int bh  = blockIdx.x;
    const int b   = bh >> 7;
    const int h   = bh & (HH - 1);
    const int tid = threadIdx.x;
    const int cg  = tid >> 5;
    const int wl  = tid & 31;
    float acc[8][16];
    #pragma unroll
    for (int j = 0; j < 8; ++j) {
        const float bj = bsum[cg * 8 + j];
        #pragma unroll
        for (int i = 0; i < 16; ++i) acc[j][i] = bj;
    }
    const float* xrowbase = x + ((size_t)(b * CIN) * HH + h) * WW;
    for (int s = 0; s < CIN / CI_STAGE; ++s) {
        __syncthreads();
        for (int f = tid; f < CI_STAGE * PADW; f += 256) {
            int r = f / PADW, cc = f - r * PADW;
            xsf[r][cc] = 0.f;
            xsf[r][PADW + WW + cc] = 0.f;
        }
        #pragma unroll
        for (int j = 0; j < 8; ++j) {
            int flat = j * 256 + tid;
            int r = flat >> 7, c4 = flat & 127;
            const float4 v = *reinterpret_cast<const float4*>(
                xrowbase + (size_t)(s * CI_STAGE + r) * HW + c4 * 4);
            *reinterpret_cast<float4*>(&xsf[r][PADW + c4 * 4]) = v;
        }
        __syncthreads();
        for (int r = 0; r < CI_STAGE; ++r) {
            const int ci = s * CI_STAGE + r;
            const float* wrow = weff + (size_t)(ci * NTAP) * COUT + cg * 8;
            const float* xr   = &xsf[r][PADW + wl];
            #pragma unroll
            for (int t = 0; t < NTAP; ++t) {
                const float4 w0 = *reinterpret_cast<const float4*>(wrow + t * COUT);
                const float4 w1 = *reinterpret_cast<const float4*>(wrow + t * COUT + 4);
                float xvv[16];
                #pragma unroll
                for (int i = 0; i < 16; ++i) xvv[i] = xr[OFFS[t] + 32 * i];
                const float wv2[8] = {w0.x, w0.y, w0.z, w0.w, w1.x, w1.y, w1.z, w1.w};
                #pragma unroll
                for (int j = 0; j < 8; ++j)
                    #pragma unroll
                    for (int i = 0; i < 16; ++i)
                        acc[j][i] = fmaf(wv2[j], xvv[i], acc[j][i]);
            }
        }
    }
    float* outbase = out + (((size_t)b * COUT + cg * 8) * HH + h) * WW + wl;
    #pragma unroll
    for (int j = 0; j < 8; ++j)
        #pragma unroll
        for (int i = 0; i < 16; ++i) {
            float v = acc[j][i];
            outbase[(size_t)j * HW + 32 * i] = v > 0.f ? v : 0.f;
        }
}

// ---------------------------------------------------------------------------

extern "C" void kernel_launch(void* const* d_in, const int* in_sizes, int n_in,
                              void* d_out, int out_size, void* d_ws, size_t ws_size,
                              hipStream_t stream) {
    const float* x  = (const float*)d_in[0];
    const float* W  = (const float*)d_in[1];
    const float* Bv = (const float*)d_in[2];
    float* out = (float*)d_out;

    const size_t need = 139264 + 256;              // wf + bsum

    if (ws_size >= need) {
        __hip_bfloat16* wf = (__hip_bfloat16*)d_ws;               // 139,264 B
        float* bsum = (float*)((char*)d_ws + 139264);             // 256 B
        prep_wfrag<<<272, 256, 0, stream>>>(W, Bv, wf, bsum);
        (void)hipFuncSetAttribute((const void*)hdc_mfma,
            hipFuncAttributeMaxDynamicSharedMemorySize, 2 * BUFB);
        hdc_mfma<<<256, 512, 2 * BUFB, stream>>>(x, wf, bsum, out);
    } else {
        float* weff = (float*)d_ws;
        float* bsum = weff + (size_t)CIN * NTAP * COUT;
        prep_weff_fb<<<(CIN * NTAP * COUT + 255) / 256, 256, 0, stream>>>(W, Bv, weff, bsum);
        hdc_fb<<<NB * HH, 256, 0, stream>>>(x, weff, bsum, out);
    }
}